// Round 19
// baseline (115.604 us; speedup 1.0000x reference)
//
#include <hip/hip_runtime.h>
#include <hip/hip_bf16.h>
#include <stdint.h>

// Problem: B=2, N=2048, D=1024, H=16, Hd=64.  All inputs fp32.
// Pipeline (3 launches): QKV GEMM (reg-staged fp32->bf16 A and B, T14
// issue-early/write-late, double-buffered single-barrier K-loop, XCD-grouped
// grid, LDS-transposed frag-major epilogue), flash attention (R18 body,
// untouched), proj GEMM (gload_lds bf16 A + reg-staged fp32 B).
// cast_all is GONE -- conversion happens in-register during GEMM staging.

typedef __bf16 bf16;
typedef __bf16 bf16x2 __attribute__((ext_vector_type(2)));
typedef __bf16 bf16x8 __attribute__((ext_vector_type(8)));
typedef float  f32x4  __attribute__((ext_vector_type(4)));
typedef float  f32x16 __attribute__((ext_vector_type(16)));
typedef uint32_t u32x4 __attribute__((ext_vector_type(4)));

#define QSCALE 0.18033688011112042f   /* 0.125 * log2(e) */

__device__ __forceinline__ void gload_lds16(const void* g, void* l) {
    __builtin_amdgcn_global_load_lds(
        (const __attribute__((address_space(1))) void*)(uintptr_t)g,
        (__attribute__((address_space(3))) void*)(uint32_t)(uintptr_t)l,
        16, 0, 0);
}

// bf16x2 vector build -> single v_cvt_pk_bf16_f32
__device__ __forceinline__ uint32_t pkbf(float a, float b) {
    bf16x2 t = { (bf16)a, (bf16)b };
    return __builtin_bit_cast(uint32_t, t);
}

// 8 floats (two f32x4) -> bf16x8 via 4 cvt_pk
__device__ __forceinline__ bf16x8 pk8(const f32x4& a, const f32x4& b) {
    union { uint32_t u[4]; bf16x8 v; } r;
    r.u[0] = pkbf(a[0], a[1]);
    r.u[1] = pkbf(a[2], a[3]);
    r.u[2] = pkbf(b[0], b[1]);
    r.u[3] = pkbf(b[2], b[3]);
    return r.v;
}

// ---------------- 128x128 bf16 MFMA GEMM, C = A * B^T (+bias) ----------------
// Staging: fp32 operands are loaded to regs EARLY (iteration top), converted
// and ds_written LATE (after compute) -- T14: HBM latency hides under MFMA.
// LDS layout identical to the proven gload_lds version (chunk c at as+c*8).
// EPI==0: A = x fp32 (reg), B = qkv_w fp32 (reg).  1-D XCD-grouped grid 768.
//         QKV epilogue via LDS transpose (ct overlays dead staging).
// EPI==1: A = att bf16 (gload_lds), B = proj_w fp32 (reg).  Grid (8,32).
template<int EPI>
__global__ __launch_bounds__(256) void gemm128(
    const float* __restrict__ Af,   // EPI0: x fp32
    const bf16*  __restrict__ Ab,   // EPI1: att bf16
    const float* __restrict__ Bwf,  // fp32 weights [Nout][K]
    const float* __restrict__ bias,
    float* __restrict__ outF,
    bf16* __restrict__ qb, bf16* __restrict__ kf, bf16* __restrict__ vf,
    int K)
{
    __shared__ __align__(16) char gsm[EPI == 0 ? 36864 : 32768];
    bf16* ct = (bf16*)gsm;                 // [128][144] padded C-tile (EPI==0)
    const int tid  = threadIdx.x;
    const int lane = tid & 63, w = tid >> 6;
    const int g = lane >> 4, lr = lane & 15;
    const int wr2 = w >> 1, wc = w & 1;
    int mt, nt;
    if (EPI == 0) {                        // 1-D XCD-grouped grid (768 blocks)
        int bid = blockIdx.x;
        int xcd = bid & 7, i = bid >> 3;   // i in [0,96)
        mt = xcd * 4 + i / 24;
        nt = i % 24;
    } else {
        nt = blockIdx.x; mt = blockIdx.y;
    }
    const int mbase = mt * 128, nbase = nt * 128;

    f32x4 acc[4][4] = {};

    // chunk c0 = tid -> row r0, kcol k0 ; chunk c1 = 256+tid -> row r0+64, k0
    const int r0 = tid >> 2, k0 = (tid & 3) * 8;
    const int r1 = r0 + 64;
    f32x4 tA[4], tB[4];

    auto ldA = [&](int it) {               // EPI0: x fp32 -> regs
        const float* Ag = Af + (size_t)mbase * K + it * 32;
        tA[0] = *(const f32x4*)(Ag + (size_t)r0 * K + k0);
        tA[1] = *(const f32x4*)(Ag + (size_t)r0 * K + k0 + 4);
        tA[2] = *(const f32x4*)(Ag + (size_t)r1 * K + k0);
        tA[3] = *(const f32x4*)(Ag + (size_t)r1 * K + k0 + 4);
    };
    auto ldAlds = [&](int buf, int it) {   // EPI1: att bf16 -> LDS direct
        const bf16* Ag = Ab + (size_t)mbase * K + it * 32;
        bf16* as = (bf16*)(gsm + buf * 16384);
        gload_lds16(Ag + (size_t)r0 * K + k0, as + tid * 8);
        gload_lds16(Ag + (size_t)r1 * K + k0, as + (256 + tid) * 8);
    };
    auto ldB = [&](int it) {               // weights fp32 -> regs
        const float* Bg = Bwf + (size_t)nbase * K + it * 32;
        tB[0] = *(const f32x4*)(Bg + (size_t)r0 * K + k0);
        tB[1] = *(const f32x4*)(Bg + (size_t)r0 * K + k0 + 4);
        tB[2] = *(const f32x4*)(Bg + (size_t)r1 * K + k0);
        tB[3] = *(const f32x4*)(Bg + (size_t)r1 * K + k0 + 4);
    };
    auto wrstg = [&](int buf) {            // cvt + ds_write (late)
        bf16* as = (bf16*)(gsm + buf * 16384);
        bf16* bs = as + 4096;
        if (EPI == 0) {
            *(bf16x8*)(as + tid * 8)         = pk8(tA[0], tA[1]);
            *(bf16x8*)(as + (256 + tid) * 8) = pk8(tA[2], tA[3]);
        }
        *(bf16x8*)(bs + tid * 8)         = pk8(tB[0], tB[1]);
        *(bf16x8*)(bs + (256 + tid) * 8) = pk8(tB[2], tB[3]);
    };

    const int nIt = K >> 5;
    if (EPI == 0) ldA(0); else ldAlds(0, 0);
    ldB(0);
    wrstg(0);
    __syncthreads();                       // publish K-step 0 (vm+lgkm drained)

    #pragma unroll 2
    for (int it = 0; it < nIt; ++it) {
        const int cur = it & 1;
        const bool pf = (it + 1 < nIt);
        if (pf) {                          // T14: issue loads early
            if (EPI == 0) ldA(it + 1); else ldAlds(cur ^ 1, it + 1);
            ldB(it + 1);
        }

        const bf16* as = (const bf16*)(gsm + cur * 16384);
        const bf16* bs = as + 4096;
        bf16x8 af[4], bfr[4];
        #pragma unroll
        for (int mi = 0; mi < 4; ++mi)
            af[mi] = *(const bf16x8*)(as + (wr2 * 64 + mi * 16 + lr) * 32 + g * 8);
        #pragma unroll
        for (int ni = 0; ni < 4; ++ni)
            bfr[ni] = *(const bf16x8*)(bs + (wc * 64 + ni * 16 + lr) * 32 + g * 8);
        #pragma unroll
        for (int mi = 0; mi < 4; ++mi)
            #pragma unroll
            for (int ni = 0; ni < 4; ++ni)
                acc[mi][ni] = __builtin_amdgcn_mfma_f32_16x16x32_bf16(
                    af[mi], bfr[ni], acc[mi][ni], 0, 0, 0);

        if (pf) wrstg(cur ^ 1);            // T14: cvt+write late (latency covered)
        __syncthreads();                   // buf[cur] reusable; stage visible
    }

    if (EPI == 1) {
        #pragma unroll
        for (int ni = 0; ni < 4; ++ni) {
            int e = nbase + wc * 64 + ni * 16 + lr;
            float bv = bias[e];
            #pragma unroll
            for (int mi = 0; mi < 4; ++mi) {
                #pragma unroll
                for (int r = 0; r < 4; ++r) {
                    int token = mbase + wr2 * 64 + mi * 16 + g * 4 + r;
                    outF[(size_t)token * 1024 + e] = acc[mi][ni][r] + bv;
                }
            }
        }
    } else {
        const int sec = nbase >> 10;                 // 0=Q 1=K 2=V
        #pragma unroll
        for (int ni = 0; ni < 4; ++ni) {
            int ec = wc * 64 + ni * 16 + lr;
            float bv = bias[nbase + ec];
            #pragma unroll
            for (int mi = 0; mi < 4; ++mi) {
                #pragma unroll
                for (int r = 0; r < 4; ++r) {
                    int tl = wr2 * 64 + mi * 16 + g * 4 + r;
                    float v = acc[mi][ni][r] + bv;
                    if (sec == 0) v *= QSCALE;
                    int row = (sec == 2) ? ec : tl;
                    int col = (sec == 2) ? tl : ec;
                    ct[row * 144 + col] = (bf16)v;
                }
            }
        }
        __syncthreads();
        const int b  = mbase >> 11;
        const int h0 = (nbase & 1023) >> 6;
        const int mb = mbase & 2047;
        #pragma unroll
        for (int si = 0; si < 8; ++si) {
            int c   = si * 256 + tid;
            int hh  = c >> 10;
            int w10 = c & 1023;
            int bh  = b * 16 + h0 + hh;
            int lrow, lcol;
            size_t gaddr;
            bf16* dst;
            if (sec == 0) {
                int nl = w10 >> 3, d0 = (w10 & 7) * 8;
                lrow = nl; lcol = hh * 64 + d0;
                gaddr = ((size_t)bh * 2048 + mb + nl) * 64 + d0;
                dst = qb;
            } else if (sec == 1) {
                int o = w10 * 8;
                int frag = o >> 9, l = (o >> 3) & 63;
                int nl = (frag >> 2) * 32 + (l & 31);
                int d0 = (frag & 3) * 16 + (l >> 5) * 8;
                lrow = nl; lcol = hh * 64 + d0;
                gaddr = ((size_t)(bh * 64 + (mb >> 5))) * 2048 + o;
                dst = kf;
            } else {
                int o = w10 * 8;
                int n6 = o >> 12, r2 = o & 4095;
                int d5 = r2 >> 11, r3 = r2 & 2047;
                int nc = r3 >> 9,  l  = (r3 >> 3) & 63;
                int d  = d5 * 32 + (l & 31);
                int n0 = n6 * 64 + nc * 16 + (l >> 5) * 8;
                lrow = hh * 64 + d; lcol = n0;
                gaddr = ((size_t)(bh * 32 + (mb >> 6))) * 4096 + o;
                dst = vf;
            }
            *(bf16x8*)(dst + gaddr) = *(const bf16x8*)(&ct[lrow * 144 + lcol]);
        }
    }
}

// ---------------- flash attention: 8 waves, KV-split, 64 q-rows per wave ----
// R18 body -- UNTOUCHED.
__global__ __launch_bounds__(512, 2) void attn32(
    const bf16* __restrict__ Q,    // [BH][N][64]
    const bf16* __restrict__ Kf,   // frag-major, 4096 elems per 64-kv chunk
    const bf16* __restrict__ Vf,   // frag-major, 4096 elems per 64-kv chunk
    bf16* __restrict__ Ao,         // [B*N][1024]
    int Nseq)
{
    __shared__ __align__(16) char smem[65536];
    bf16*  KsB = (bf16*)smem;              // [half][buf][4096]
    bf16*  VsB = (bf16*)(smem + 32768);    // [half][buf][4096]
    float* xch = (float*)smem;             // overlay: [4][64][36] partials
    bf16*  otp = (bf16*)(smem + 36864);    // overlay: [4][32][66] out transpose

    const int tid  = threadIdx.x;
    const int lane = tid & 63;
    const int u    = tid >> 6;             // wave 0..7
    const int half = u >> 2, qw = u & 3;
    const int hi = lane >> 5, ql = lane & 31;
    const int bid = blockIdx.x;            // 256 blocks
    const int xcd = bid & 7, ii = bid >> 3;
    const int bh = xcd * 4 + (ii >> 3), qc = ii & 7;
    const int h = bh & 15, b = bh >> 4;
    const int q0 = qc * 256 + qw * 64;

    const bf16* Qh  = Q  + (size_t)bh * Nseq * 64;
    const bf16* Kfh = Kf + (size_t)bh * Nseq * 64;
    const bf16* Vfh = Vf + (size_t)bh * Nseq * 64;

    bf16x8 qfA[4], qfB[4];
    #pragma unroll
    for (int c = 0; c < 4; ++c) {
        qfA[c] = *(const bf16x8*)(Qh + (size_t)(q0 + ql) * 64 + c * 16 + hi * 8);
        qfB[c] = *(const bf16x8*)(Qh + (size_t)(q0 + 32 + ql) * 64 + c * 16 + hi * 8);
    }

    bf16x8 vones;
    #pragma unroll
    for (int i = 0; i < 8; ++i) vones[i] = (bf16)1.0f;

    f32x16 o0A = {}, o1A = {}, laA = {};
    f32x16 o0B = {}, o1B = {}, laB = {};

    const int nch = (Nseq >> 6) >> 1;
    const int hk  = half * nch;

    auto stage = [&](int buf, int t) {
        const bf16* Kc = Kfh + (size_t)(hk + t) * 4096;
        const bf16* Vc = Vfh + (size_t)(hk + t) * 4096;
        bf16* kd = KsB + (half * 2 + buf) * 4096;
        bf16* vd = VsB + (half * 2 + buf) * 4096;
        int ht = tid & 255;
        gload_lds16(Kc + ht * 8,        kd + ht * 8);
        gload_lds16(Kc + 2048 + ht * 8, kd + 2048 + ht * 8);
        gload_lds16(Vc + ht * 8,        vd + ht * 8);
        gload_lds16(Vc + 2048 + ht * 8, vd + 2048 + ht * 8);
    };

    stage(0, 0);
    __syncthreads();

    #pragma unroll 2
    for (int t = 0; t < nch; ++t) {
        const int cur = t & 1;
        if (t + 1 < nch) stage(cur ^ 1, t + 1);

        const bf16* kl = KsB + (half * 2 + cur) * 4096;
        const bf16* vl = VsB + (half * 2 + cur) * 4096;
        bf16x8 kin[8], vfr[8];
        #pragma unroll
        for (int i = 0; i < 8; ++i)
            kin[i] = *(const bf16x8*)(kl + i * 512 + lane * 8);
        #pragma unroll
        for (int i = 0; i < 8; ++i)
            vfr[i] = *(const bf16x8*)(vl + i * 512 + lane * 8);

        // ---- tile A ----
        {
            f32x16 s0 = {}, s1 = {};
            #pragma unroll
            for (int c = 0; c < 4; ++c) {
                s0 = __builtin_amdgcn_mfma_f32_32x32x16_bf16(kin[c],     qfA[c], s0, 0, 0, 0);
                s1 = __builtin_amdgcn_mfma_f32_32x32x16_bf16(kin[4 + c], qfA[c], s1, 0, 0, 0);
            }
            float p0[16], p1[16];
            #pragma unroll
            for (int r = 0; r < 16; ++r) { p0[r] = __builtin_amdgcn_exp2f(s0[r]); }
            #pragma unroll
            for (int r = 0; r < 16; ++r) { p1[r] = __builtin_amdgcn_exp2f(s1[r]); }
            bf16x8 pfr[4];
            #pragma unroll
            for (int f = 0; f < 4; ++f) {
                const float* pp = (f < 2) ? p0 : p1;
                const int base = (f & 1) * 8;
                union { uint32_t u[4]; bf16x8 v; } pw;
                #pragma unroll
                for (int wd = 0; wd < 2; ++wd) {
                    uint32_t X = pkbf(pp[base + 2*wd], pp[base + 2*wd + 1]);
                    uint32_t Y = pkbf(pp[base + 4 + 2*wd], pp[base + 4 + 2*wd + 1]);
                    auto rr = __builtin_amdgcn_permlane32_swap((int)X, (int)Y, false, false);
                    pw.u[wd]     = (uint32_t)rr[0];
                    pw.u[2 + wd] = (uint32_t)rr[1];
                }
                pfr[f] = pw.v;
            }
            #pragma unroll
            for (int f = 0; f < 4; ++f) {
                o0A = __builtin_amdgcn_mfma_f32_32x32x16_bf16(vfr[f],     pfr[f], o0A, 0, 0, 0);
                o1A = __builtin_amdgcn_mfma_f32_32x32x16_bf16(vfr[4 + f], pfr[f], o1A, 0, 0, 0);
                laA = __builtin_amdgcn_mfma_f32_32x32x16_bf16(vones,      pfr[f], laA, 0, 0, 0);
            }
        }
        // ---- tile B ----
        {
            f32x16 s0 = {}, s1 = {};
            #pragma unroll
            for (int c = 0; c < 4; ++c) {
                s0 = __builtin_amdgcn_mfma_f32_32x32x16_bf16(kin[c],     qfB[c], s0, 0, 0, 0);
                s1 = __builtin_amdgcn_mfma_f32_32x32x16_bf16(kin[4 + c], qfB[c], s1, 0, 0, 0);
            }
            float p0[16], p1[16];
            #pragma unroll
            for (int r = 0; r < 16; ++r) { p0[r] = __builtin_amdgcn_exp2f(s0[r]); }
            #pragma unroll
            for (int r = 0; r < 16; ++r) { p1[r] = __builtin_amdgcn_exp2f(s1[r]); }
            bf16x8 pfr[4];
            #pragma unroll
            for (int f = 0; f < 4; ++f) {
                const float* pp = (f < 2) ? p0 : p1;
                const int base = (f & 1) * 8;
                union { uint32_t u[4]; bf16x8 v; } pw;
                #pragma unroll
                for (int wd = 0; wd < 2; ++wd) {
                    uint32_t X = pkbf(pp[base + 2*wd], pp[base + 2*wd + 1]);
                    uint32_t Y = pkbf(pp[base + 4 + 2*wd], pp[base + 4 + 2*wd + 1]);
                    auto rr = __builtin_amdgcn_permlane32_swap((int)X, (int)Y, false, false);
                    pw.u[wd]     = (uint32_t)rr[0];
                    pw.u[2 + wd] = (uint32_t)rr[1];
                }
                pfr[f] = pw.v;
            }
            #pragma unroll
            for (int f = 0; f < 4; ++f) {
                o0B = __builtin_amdgcn_mfma_f32_32x32x16_bf16(vfr[f],     pfr[f], o0B, 0, 0, 0);
                o1B = __builtin_amdgcn_mfma_f32_32x32x16_bf16(vfr[4 + f], pfr[f], o1B, 0, 0, 0);
                laB = __builtin_amdgcn_mfma_f32_32x32x16_bf16(vones,      pfr[f], laB, 0, 0, 0);
            }
        }

        __syncthreads();
    }

    auto finish = [&](const f32x16& po0, const f32x16& po1, const f32x16& pla, int qp) {
        float lsum = pla[0];
        __syncthreads();
        if (half == 1) {
            float* xp = xch + ((size_t)(qw * 64 + lane)) * 36;
            *(f32x16*)(xp)      = po0;
            *(f32x16*)(xp + 16) = po1;
            xp[32] = lsum;
        }
        __syncthreads();
        if (half == 0) {
            const float* xp = xch + ((size_t)(qw * 64 + lane)) * 36;
            f32x16 oa = *(const f32x16*)(xp);
            f32x16 ob = *(const f32x16*)(xp + 16);
            f32x16 m0 = po0 + oa;
            f32x16 m1 = po1 + ob;
            float ls = lsum + xp[32];
            float linv = __builtin_amdgcn_rcpf(ls);
            #pragma unroll
            for (int qd = 0; qd < 4; ++qd) {
                int dbase = 8 * qd + 4 * hi;
                bf16* orow = otp + (qw * 32 + ql) * 66;
                *(uint32_t*)(orow + dbase)          = pkbf(m0[4*qd] * linv,   m0[4*qd+1] * linv);
                *(uint32_t*)(orow + dbase + 2)      = pkbf(m0[4*qd+2] * linv, m0[4*qd+3] * linv);
                *(uint32_t*)(orow + 32 + dbase)     = pkbf(m1[4*qd] * linv,   m1[4*qd+1] * linv);
                *(uint32_t*)(orow + 32 + dbase + 2) = pkbf(m1[4*qd+2] * linv, m1[4*qd+3] * linv);
            }
            __asm__ volatile("s_waitcnt lgkmcnt(0)" ::: "memory");
            const int t = lane >> 1, e = lane & 1;
            uint32_t rw[16];
            #pragma unroll
            for (int j = 0; j < 16; ++j)
                rw[j] = *(const uint32_t*)(otp + (qw * 32 + t) * 66 + e * 32 + 2 * j);
            size_t gbase = (size_t)(b * Nseq + q0 + qp + t) * 1024 + h * 64 + e * 32;
            #pragma unroll
            for (int v = 0; v < 4; ++v) {
                u32x4 sv = { rw[4*v], rw[4*v+1], rw[4*v+2], rw[4*v+3] };
                *(u32x4*)(Ao + gbase + v * 8) = sv;
            }
        }
    };
    finish(o0A, o1A, laA, 0);
    finish(o0B, o1B, laB, 32);
}

extern "C" void kernel_launch(void* const* d_in, const int* in_sizes, int n_in,
                              void* d_out, int out_size, void* d_ws, size_t ws_size,
                              hipStream_t stream) {
    const float* x      = (const float*)d_in[0];
    const float* qkv_w  = (const float*)d_in[1];
    const float* qkv_b  = (const float*)d_in[2];
    const float* proj_w = (const float*)d_in[3];
    const float* proj_b = (const float*)d_in[4];
    float* out = (float*)d_out;

    char* ws = (char*)d_ws;
    bf16* qb    = (bf16*)(ws + ((size_t)16 << 20));  // 8 MB  [32][2048][64]
    bf16* kf    = (bf16*)(ws + ((size_t)24 << 20));  // 8 MB  fragment-major K
    bf16* vf    = (bf16*)(ws + ((size_t)32 << 20));  // 8 MB  fragment-major V
    bf16* att   = (bf16*)(ws);                       // 8 MB  [4096][1024]

    gemm128<0><<<dim3(768), dim3(256), 0, stream>>>(
        x, (const bf16*)nullptr, qkv_w, qkv_b, (float*)nullptr, qb, kf, vf, 1024);

    attn32<<<dim3(256), dim3(512), 0, stream>>>(qb, kf, vf, att, 2048);

    gemm128<1><<<dim3(8, 32), dim3(256), 0, stream>>>(
        (const float*)nullptr, att, proj_w, proj_b, out,
        (bf16*)nullptr, (bf16*)nullptr, (bf16*)nullptr, 1024);
}

// Round 20
// 106.845 us; speedup vs baseline: 1.0820x; 1.0820x over previous
//
#include <hip/hip_runtime.h>
#include <hip/hip_bf16.h>
#include <stdint.h>

// Problem: B=2, N=2048, D=1024, H=16, Hd=64.  All inputs fp32.
// R18 known-good configuration (106.7 us), byte-exact revert from the R19
// reg-staging regression (fp32 fetch doubled FETCH_SIZE + ds_write bank
// conflicts).  Pipeline: fused cast->bf16, QKV GEMM (128x128 MFMA,
// double-buffered LDS single-barrier K-loop via global_load_lds, XCD-grouped
// 1-D grid, LDS-transposed coalesced frag-major epilogue overlaid on
// staging), flash attention (in-block KV-split, 8-wave blocks, 64 q-rows/wave,
// ones-MFMA denominator), proj GEMM.

typedef __bf16 bf16;
typedef __bf16 bf16x2 __attribute__((ext_vector_type(2)));
typedef __bf16 bf16x4 __attribute__((ext_vector_type(4)));
typedef __bf16 bf16x8 __attribute__((ext_vector_type(8)));
typedef float  f32x4  __attribute__((ext_vector_type(4)));
typedef float  f32x16 __attribute__((ext_vector_type(16)));
typedef uint32_t u32x4 __attribute__((ext_vector_type(4)));

#define QSCALE 0.18033688011112042f   /* 0.125 * log2(e) */

__device__ __forceinline__ void gload_lds16(const void* g, void* l) {
    __builtin_amdgcn_global_load_lds(
        (const __attribute__((address_space(1))) void*)(uintptr_t)g,
        (__attribute__((address_space(3))) void*)(uint32_t)(uintptr_t)l,
        16, 0, 0);
}

// bf16x2 vector build -> single v_cvt_pk_bf16_f32
__device__ __forceinline__ uint32_t pkbf(float a, float b) {
    bf16x2 t = { (bf16)a, (bf16)b };
    return __builtin_bit_cast(uint32_t, t);
}

// ---------------- fused cast fp32 -> bf16 (one launch for x, qkv_w, proj_w) --
__global__ void cast_all(const float* __restrict__ x,
                         const float* __restrict__ qw,
                         const float* __restrict__ pw,
                         bf16* __restrict__ xb, bf16* __restrict__ wq,
                         bf16* __restrict__ wp) {
    int i = blockIdx.x * blockDim.x + threadIdx.x;
    const float4* src; bf16x4* dst; int off;
    if (i < 1048576)      { src = (const float4*)x;  dst = (bf16x4*)xb; off = i; }
    else if (i < 1835008) { src = (const float4*)qw; dst = (bf16x4*)wq; off = i - 1048576; }
    else                  { src = (const float4*)pw; dst = (bf16x4*)wp; off = i - 1835008; }
    float4 v = src[off];
    bf16x4 o = { (bf16)v.x, (bf16)v.y, (bf16)v.z, (bf16)v.w };
    dst[off] = o;
}

// ---------------- 128x128 bf16 MFMA GEMM, C = A * B^T (+bias) ----------------
// Double-buffered LDS staging via global_load_lds, ONE __syncthreads per
// K-step.  EPI==0: 1-D grid 768, XCD-grouped; QKV epilogue via LDS transpose.
// EPI==1: proj epilogue -> fp32 out[token][1024] (+bias), direct stores.
template<int EPI>
__global__ __launch_bounds__(256) void gemm128(
    const bf16* __restrict__ A,
    const bf16* __restrict__ Bw,
    const float* __restrict__ bias,
    float* __restrict__ outF,
    bf16* __restrict__ qb, bf16* __restrict__ kf, bf16* __restrict__ vf,
    int K)
{
    __shared__ __align__(16) char gsm[EPI == 0 ? 36864 : 32768];
    bf16* ct = (bf16*)gsm;                 // [128][144] padded C-tile (EPI==0)
    const int tid  = threadIdx.x;
    const int lane = tid & 63, w = tid >> 6;
    const int g = lane >> 4, lr = lane & 15;
    const int wr = w >> 1, wc = w & 1;
    int mt, nt;
    if (EPI == 0) {                        // 1-D XCD-grouped grid (768 blocks)
        int bid = blockIdx.x;
        int xcd = bid & 7, i = bid >> 3;   // i in [0,96)
        mt = xcd * 4 + i / 24;
        nt = i % 24;
    } else {
        nt = blockIdx.x; mt = blockIdx.y;
    }
    const int mbase = mt * 128, nbase = nt * 128;

    f32x4 acc[4][4] = {};

    auto stg = [&](int buf, int it) {
        const bf16* Ag = A  + (size_t)mbase * K + it * 32;
        const bf16* Bg = Bw + (size_t)nbase * K + it * 32;
        bf16* as = (bf16*)(gsm + buf * 16384);
        bf16* bs = (bf16*)(gsm + buf * 16384 + 8192);
        int c0 = tid, c1 = 256 + tid;
        gload_lds16(Ag + (size_t)(c0 >> 2) * K + (c0 & 3) * 8, as + c0 * 8);
        gload_lds16(Bg + (size_t)(c0 >> 2) * K + (c0 & 3) * 8, bs + c0 * 8);
        gload_lds16(Ag + (size_t)(c1 >> 2) * K + (c1 & 3) * 8, as + c1 * 8);
        gload_lds16(Bg + (size_t)(c1 >> 2) * K + (c1 & 3) * 8, bs + c1 * 8);
    };

    const int nIt = K >> 5;
    stg(0, 0);
    __syncthreads();                       // publish K-step 0

    #pragma unroll 2
    for (int it = 0; it < nIt; ++it) {
        const int cur = it & 1;
        if (it + 1 < nIt) stg(cur ^ 1, it + 1);   // prefetch overlaps compute

        const bf16* as = (const bf16*)(gsm + cur * 16384);
        const bf16* bs = as + 4096;
        bf16x8 af[4], bfr[4];
        #pragma unroll
        for (int mi = 0; mi < 4; ++mi)
            af[mi] = *(const bf16x8*)(as + (wr * 64 + mi * 16 + lr) * 32 + g * 8);
        #pragma unroll
        for (int ni = 0; ni < 4; ++ni)
            bfr[ni] = *(const bf16x8*)(bs + (wc * 64 + ni * 16 + lr) * 32 + g * 8);
        #pragma unroll
        for (int mi = 0; mi < 4; ++mi)
            #pragma unroll
            for (int ni = 0; ni < 4; ++ni)
                acc[mi][ni] = __builtin_amdgcn_mfma_f32_16x16x32_bf16(
                    af[mi], bfr[ni], acc[mi][ni], 0, 0, 0);

        __syncthreads();   // vmcnt(0): stg(it+1) done; barrier: buf[cur] reusable
    }

    if (EPI == 1) {
        #pragma unroll
        for (int ni = 0; ni < 4; ++ni) {
            int e = nbase + wc * 64 + ni * 16 + lr;
            float bv = bias[e];
            #pragma unroll
            for (int mi = 0; mi < 4; ++mi) {
                #pragma unroll
                for (int r = 0; r < 4; ++r) {
                    int token = mbase + wr * 64 + mi * 16 + g * 4 + r;
                    outF[(size_t)token * 1024 + e] = acc[mi][ni][r] + bv;
                }
            }
        }
    } else {
        const int sec = nbase >> 10;                 // 0=Q 1=K 2=V (tile never straddles)
        #pragma unroll
        for (int ni = 0; ni < 4; ++ni) {
            int ec = wc * 64 + ni * 16 + lr;
            float bv = bias[nbase + ec];
            #pragma unroll
            for (int mi = 0; mi < 4; ++mi) {
                #pragma unroll
                for (int r = 0; r < 4; ++r) {
                    int tl = wr * 64 + mi * 16 + g * 4 + r;
                    float v = acc[mi][ni][r] + bv;
                    if (sec == 0) v *= QSCALE;
                    int row = (sec == 2) ? ec : tl;
                    int col = (sec == 2) ? tl : ec;
                    ct[row * 144 + col] = (bf16)v;
                }
            }
        }
        __syncthreads();
        const int b  = mbase >> 11;
        const int h0 = (nbase & 1023) >> 6;
        const int mb = mbase & 2047;
        #pragma unroll
        for (int si = 0; si < 8; ++si) {
            int c   = si * 256 + tid;
            int hh  = c >> 10;
            int w10 = c & 1023;
            int bh  = b * 16 + h0 + hh;
            int lrow, lcol;
            size_t gaddr;
            bf16* dst;
            if (sec == 0) {
                int nl = w10 >> 3, d0 = (w10 & 7) * 8;
                lrow = nl; lcol = hh * 64 + d0;
                gaddr = ((size_t)bh * 2048 + mb + nl) * 64 + d0;
                dst = qb;
            } else if (sec == 1) {
                int o = w10 * 8;
                int frag = o >> 9, l = (o >> 3) & 63;
                int nl = (frag >> 2) * 32 + (l & 31);
                int d0 = (frag & 3) * 16 + (l >> 5) * 8;
                lrow = nl; lcol = hh * 64 + d0;
                gaddr = ((size_t)(bh * 64 + (mb >> 5))) * 2048 + o;
                dst = kf;
            } else {
                int o = w10 * 8;
                int n6 = o >> 12, r2 = o & 4095;
                int d5 = r2 >> 11, r3 = r2 & 2047;
                int nc = r3 >> 9,  l  = (r3 >> 3) & 63;
                int d  = d5 * 32 + (l & 31);
                int n0 = n6 * 64 + nc * 16 + (l >> 5) * 8;
                lrow = hh * 64 + d; lcol = n0;
                gaddr = ((size_t)(bh * 32 + (mb >> 6))) * 4096 + o;
                dst = vf;
            }
            *(bf16x8*)(dst + gaddr) = *(const bf16x8*)(&ct[lrow * 144 + lcol]);
        }
    }
}

// ---------------- flash attention: 8 waves, KV-split, 64 q-rows per wave ----
// 256 blocks x 512 threads, __launch_bounds__(512,2).
// Waves 0-3 = kv [0,1024), waves 4-7 = kv [1024,2048); each wave owns TWO
// 32-q tiles so every kin/vfr fragment read feeds 2x the MFMA work.
// Denominator via ones-MFMA.  Epilogue merges halves in 2 passes.
__global__ __launch_bounds__(512, 2) void attn32(
    const bf16* __restrict__ Q,    // [BH][N][64]
    const bf16* __restrict__ Kf,   // frag-major, 4096 elems per 64-kv chunk
    const bf16* __restrict__ Vf,   // frag-major, 4096 elems per 64-kv chunk
    bf16* __restrict__ Ao,         // [B*N][1024]
    int Nseq)
{
    __shared__ __align__(16) char smem[65536];
    bf16*  KsB = (bf16*)smem;              // [half][buf][4096]
    bf16*  VsB = (bf16*)(smem + 32768);    // [half][buf][4096]
    float* xch = (float*)smem;             // overlay: [4][64][36] partials
    bf16*  otp = (bf16*)(smem + 36864);    // overlay: [4][32][66] out transpose

    const int tid  = threadIdx.x;
    const int lane = tid & 63;
    const int u    = tid >> 6;             // wave 0..7
    const int half = u >> 2, qw = u & 3;
    const int hi = lane >> 5, ql = lane & 31;
    const int bid = blockIdx.x;            // 256 blocks
    const int xcd = bid & 7, ii = bid >> 3;
    const int bh = xcd * 4 + (ii >> 3), qc = ii & 7;
    const int h = bh & 15, b = bh >> 4;
    const int q0 = qc * 256 + qw * 64;

    const bf16* Qh  = Q  + (size_t)bh * Nseq * 64;
    const bf16* Kfh = Kf + (size_t)bh * Nseq * 64;
    const bf16* Vfh = Vf + (size_t)bh * Nseq * 64;

    bf16x8 qfA[4], qfB[4];
    #pragma unroll
    for (int c = 0; c < 4; ++c) {
        qfA[c] = *(const bf16x8*)(Qh + (size_t)(q0 + ql) * 64 + c * 16 + hi * 8);
        qfB[c] = *(const bf16x8*)(Qh + (size_t)(q0 + 32 + ql) * 64 + c * 16 + hi * 8);
    }

    bf16x8 vones;
    #pragma unroll
    for (int i = 0; i < 8; ++i) vones[i] = (bf16)1.0f;

    f32x16 o0A = {}, o1A = {}, laA = {};
    f32x16 o0B = {}, o1B = {}, laB = {};

    const int nch = (Nseq >> 6) >> 1;      // chunks per half (16, even)
    const int hk  = half * nch;

    auto stage = [&](int buf, int t) {
        const bf16* Kc = Kfh + (size_t)(hk + t) * 4096;
        const bf16* Vc = Vfh + (size_t)(hk + t) * 4096;
        bf16* kd = KsB + (half * 2 + buf) * 4096;
        bf16* vd = VsB + (half * 2 + buf) * 4096;
        int ht = tid & 255;
        gload_lds16(Kc + ht * 8,        kd + ht * 8);
        gload_lds16(Kc + 2048 + ht * 8, kd + 2048 + ht * 8);
        gload_lds16(Vc + ht * 8,        vd + ht * 8);
        gload_lds16(Vc + 2048 + ht * 8, vd + 2048 + ht * 8);
    };

    stage(0, 0);
    __syncthreads();                       // publish chunk 0 (vmcnt(0) + barrier)

    #pragma unroll 2
    for (int t = 0; t < nch; ++t) {
        const int cur = t & 1;
        if (t + 1 < nch) stage(cur ^ 1, t + 1);   // prefetch overlaps compute

        const bf16* kl = KsB + (half * 2 + cur) * 4096;
        const bf16* vl = VsB + (half * 2 + cur) * 4096;
        bf16x8 kin[8], vfr[8];
        #pragma unroll
        for (int i = 0; i < 8; ++i)
            kin[i] = *(const bf16x8*)(kl + i * 512 + lane * 8);
        #pragma unroll
        for (int i = 0; i < 8; ++i)
            vfr[i] = *(const bf16x8*)(vl + i * 512 + lane * 8);

        // ---- tile A ----
        {
            f32x16 s0 = {}, s1 = {};
            #pragma unroll
            for (int c = 0; c < 4; ++c) {
                s0 = __builtin_amdgcn_mfma_f32_32x32x16_bf16(kin[c],     qfA[c], s0, 0, 0, 0);
                s1 = __builtin_amdgcn_mfma_f32_32x32x16_bf16(kin[4 + c], qfA[c], s1, 0, 0, 0);
            }
            float p0[16], p1[16];
            #pragma unroll
            for (int r = 0; r < 16; ++r) { p0[r] = __builtin_amdgcn_exp2f(s0[r]); }
            #pragma unroll
            for (int r = 0; r < 16; ++r) { p1[r] = __builtin_amdgcn_exp2f(s1[r]); }
            bf16x8 pfr[4];
            #pragma unroll
            for (int f = 0; f < 4; ++f) {
                const float* pp = (f < 2) ? p0 : p1;
                const int base = (f & 1) * 8;
                union { uint32_t u[4]; bf16x8 v; } pw;
                #pragma unroll
                for (int wd = 0; wd < 2; ++wd) {
                    uint32_t X = pkbf(pp[base + 2*wd], pp[base + 2*wd + 1]);
                    uint32_t Y = pkbf(pp[base + 4 + 2*wd], pp[base + 4 + 2*wd + 1]);
                    auto rr = __builtin_amdgcn_permlane32_swap((int)X, (int)Y, false, false);
                    pw.u[wd]     = (uint32_t)rr[0];
                    pw.u[2 + wd] = (uint32_t)rr[1];
                }
                pfr[f] = pw.v;
            }
            #pragma unroll
            for (int f = 0; f < 4; ++f) {
                o0A = __builtin_amdgcn_mfma_f32_32x32x16_bf16(vfr[f],     pfr[f], o0A, 0, 0, 0);
                o1A = __builtin_amdgcn_mfma_f32_32x32x16_bf16(vfr[4 + f], pfr[f], o1A, 0, 0, 0);
                laA = __builtin_amdgcn_mfma_f32_32x32x16_bf16(vones,      pfr[f], laA, 0, 0, 0);
            }
        }
        // ---- tile B ----
        {
            f32x16 s0 = {}, s1 = {};
            #pragma unroll
            for (int c = 0; c < 4; ++c) {
                s0 = __builtin_amdgcn_mfma_f32_32x32x16_bf16(kin[c],     qfB[c], s0, 0, 0, 0);
                s1 = __builtin_amdgcn_mfma_f32_32x32x16_bf16(kin[4 + c], qfB[c], s1, 0, 0, 0);
            }
            float p0[16], p1[16];
            #pragma unroll
            for (int r = 0; r < 16; ++r) { p0[r] = __builtin_amdgcn_exp2f(s0[r]); }
            #pragma unroll
            for (int r = 0; r < 16; ++r) { p1[r] = __builtin_amdgcn_exp2f(s1[r]); }
            bf16x8 pfr[4];
            #pragma unroll
            for (int f = 0; f < 4; ++f) {
                const float* pp = (f < 2) ? p0 : p1;
                const int base = (f & 1) * 8;
                union { uint32_t u[4]; bf16x8 v; } pw;
                #pragma unroll
                for (int wd = 0; wd < 2; ++wd) {
                    uint32_t X = pkbf(pp[base + 2*wd], pp[base + 2*wd + 1]);
                    uint32_t Y = pkbf(pp[base + 4 + 2*wd], pp[base + 4 + 2*wd + 1]);
                    auto rr = __builtin_amdgcn_permlane32_swap((int)X, (int)Y, false, false);
                    pw.u[wd]     = (uint32_t)rr[0];
                    pw.u[2 + wd] = (uint32_t)rr[1];
                }
                pfr[f] = pw.v;
            }
            #pragma unroll
            for (int f = 0; f < 4; ++f) {
                o0B = __builtin_amdgcn_mfma_f32_32x32x16_bf16(vfr[f],     pfr[f], o0B, 0, 0, 0);
                o1B = __builtin_amdgcn_mfma_f32_32x32x16_bf16(vfr[4 + f], pfr[f], o1B, 0, 0, 0);
                laB = __builtin_amdgcn_mfma_f32_32x32x16_bf16(vones,      pfr[f], laB, 0, 0, 0);
            }
        }

        __syncthreads();   // vmcnt(0): stage(t+1) done; barrier: buf[cur] reusable
    }

    // ---- epilogue: two passes (tile A then B) through the same xch overlay ----
    auto finish = [&](const f32x16& po0, const f32x16& po1, const f32x16& pla, int qp) {
        float lsum = pla[0];               // ones-MFMA: denominator for q=ql
        __syncthreads();                   // staging dead / prior pass consumed
        if (half == 1) {
            float* xp = xch + ((size_t)(qw * 64 + lane)) * 36;
            *(f32x16*)(xp)      = po0;
            *(f32x16*)(xp + 16) = po1;
            xp[32] = lsum;
        }
        __syncthreads();
        if (half == 0) {
            const float* xp = xch + ((size_t)(qw * 64 + lane)) * 36;
            f32x16 oa = *(const f32x16*)(xp);
            f32x16 ob = *(const f32x16*)(xp + 16);
            f32x16 m0 = po0 + oa;
            f32x16 m1 = po1 + ob;
            float ls = lsum + xp[32];
            float linv = __builtin_amdgcn_rcpf(ls);
            #pragma unroll
            for (int qd = 0; qd < 4; ++qd) {
                int dbase = 8 * qd + 4 * hi;
                bf16* orow = otp + (qw * 32 + ql) * 66;
                *(uint32_t*)(orow + dbase)          = pkbf(m0[4*qd] * linv,   m0[4*qd+1] * linv);
                *(uint32_t*)(orow + dbase + 2)      = pkbf(m0[4*qd+2] * linv, m0[4*qd+3] * linv);
                *(uint32_t*)(orow + 32 + dbase)     = pkbf(m1[4*qd] * linv,   m1[4*qd+1] * linv);
                *(uint32_t*)(orow + 32 + dbase + 2) = pkbf(m1[4*qd+2] * linv, m1[4*qd+3] * linv);
            }
            __asm__ volatile("s_waitcnt lgkmcnt(0)" ::: "memory");
            const int t = lane >> 1, e = lane & 1;
            uint32_t rw[16];
            #pragma unroll
            for (int j = 0; j < 16; ++j)
                rw[j] = *(const uint32_t*)(otp + (qw * 32 + t) * 66 + e * 32 + 2 * j);
            size_t gbase = (size_t)(b * Nseq + q0 + qp + t) * 1024 + h * 64 + e * 32;
            #pragma unroll
            for (int v = 0; v < 4; ++v) {
                u32x4 sv = { rw[4*v], rw[4*v+1], rw[4*v+2], rw[4*v+3] };
                *(u32x4*)(Ao + gbase + v * 8) = sv;
            }
        }
    };
    finish(o0A, o1A, laA, 0);
    finish(o0B, o1B, laB, 32);
}

extern "C" void kernel_launch(void* const* d_in, const int* in_sizes, int n_in,
                              void* d_out, int out_size, void* d_ws, size_t ws_size,
                              hipStream_t stream) {
    const float* x      = (const float*)d_in[0];
    const float* qkv_w  = (const float*)d_in[1];
    const float* qkv_b  = (const float*)d_in[2];
    const float* proj_w = (const float*)d_in[3];
    const float* proj_b = (const float*)d_in[4];
    float* out = (float*)d_out;

    char* ws = (char*)d_ws;
    bf16* xb    = (bf16*)(ws);                       // 8 MB  [4096][1024]
    bf16* wqkv  = (bf16*)(ws + ((size_t)8  << 20));  // 6 MB  [3072][1024]
    bf16* wproj = (bf16*)(ws + ((size_t)14 << 20));  // 2 MB  [1024][1024]
    bf16* qb    = (bf16*)(ws + ((size_t)16 << 20));  // 8 MB  [32][2048][64]
    bf16* kf    = (bf16*)(ws + ((size_t)24 << 20));  // 8 MB  fragment-major K
    bf16* vf    = (bf16*)(ws + ((size_t)32 << 20));  // 8 MB  fragment-major V
    bf16* att   = (bf16*)(ws);                       // 8 MB  [4096][1024] (over xb)

    cast_all<<<dim3(8192), dim3(256), 0, stream>>>(x, qkv_w, proj_w, xb, wqkv, wproj);

    gemm128<0><<<dim3(768), dim3(256), 0, stream>>>(
        xb, wqkv, qkv_b, (float*)nullptr, qb, kf, vf, 1024);

    attn32<<<dim3(256), dim3(512), 0, stream>>>(qb, kf, vf, att, 2048);

    gemm128<1><<<dim3(8, 32), dim3(256), 0, stream>>>(
        att, wproj, proj_b, out, (bf16*)nullptr, (bf16*)nullptr, (bf16*)nullptr, 1024);
}

// Round 21
// 106.341 us; speedup vs baseline: 1.0871x; 1.0047x over previous
//
#include <hip/hip_runtime.h>
#include <hip/hip_bf16.h>
#include <stdint.h>

// Problem: B=2, N=2048, D=1024, H=16, Hd=64.  All inputs fp32.
// R18-lineage configuration.  Pipeline: fused cast->bf16 (grid-stride),
// QKV GEMM (128x128 MFMA, double-buffered LDS single-barrier K-loop via
// global_load_lds, XCD-grouped 1-D grid, LDS-transposed frag-major epilogue),
// flash attention (in-block KV-split, 8-wave blocks, 64 q-rows/wave,
// ones-MFMA denominator), proj GEMM (now also XCD-grouped).

typedef __bf16 bf16;
typedef __bf16 bf16x2 __attribute__((ext_vector_type(2)));
typedef __bf16 bf16x4 __attribute__((ext_vector_type(4)));
typedef __bf16 bf16x8 __attribute__((ext_vector_type(8)));
typedef float  f32x4  __attribute__((ext_vector_type(4)));
typedef float  f32x16 __attribute__((ext_vector_type(16)));
typedef uint32_t u32x4 __attribute__((ext_vector_type(4)));

#define QSCALE 0.18033688011112042f   /* 0.125 * log2(e) */

__device__ __forceinline__ void gload_lds16(const void* g, void* l) {
    __builtin_amdgcn_global_load_lds(
        (const __attribute__((address_space(1))) void*)(uintptr_t)g,
        (__attribute__((address_space(3))) void*)(uint32_t)(uintptr_t)l,
        16, 0, 0);
}

// bf16x2 vector build -> single v_cvt_pk_bf16_f32
__device__ __forceinline__ uint32_t pkbf(float a, float b) {
    bf16x2 t = { (bf16)a, (bf16)b };
    return __builtin_bit_cast(uint32_t, t);
}

// ---------------- fused cast fp32 -> bf16 (grid-stride, one launch) ---------
// float4-chunk counts: x 1048576, qkv_w 786432, proj_w 262144 (total 2097152)
__global__ void cast_all(const float* __restrict__ x,
                         const float* __restrict__ qw,
                         const float* __restrict__ pw,
                         bf16* __restrict__ xb, bf16* __restrict__ wq,
                         bf16* __restrict__ wp) {
    const int stride = 2048 * 256;
    for (int i = blockIdx.x * blockDim.x + threadIdx.x; i < 2097152; i += stride) {
        const float4* src; bf16x4* dst; int off;
        if (i < 1048576)      { src = (const float4*)x;  dst = (bf16x4*)xb; off = i; }
        else if (i < 1835008) { src = (const float4*)qw; dst = (bf16x4*)wq; off = i - 1048576; }
        else                  { src = (const float4*)pw; dst = (bf16x4*)wp; off = i - 1835008; }
        float4 v = src[off];
        bf16x4 o = { (bf16)v.x, (bf16)v.y, (bf16)v.z, (bf16)v.w };
        dst[off] = o;
    }
}

// ---------------- 128x128 bf16 MFMA GEMM, C = A * B^T (+bias) ----------------
// Double-buffered LDS staging via global_load_lds, ONE __syncthreads per
// K-step.  Both EPI variants use a 1-D XCD-grouped grid:
//   EPI==0: 768 blocks, xcd owns m-tiles [4*xcd,4*xcd+4) x 24 n-tiles.
//   EPI==1: 256 blocks, xcd owns m-tiles [4*xcd,4*xcd+4)... pattern below
//           (per-XCD L2 set: A-panels 1MB + B 2MB < 4MB -> B L2-resident).
// EPI==0 epilogue: QKV via LDS transpose (ct overlays dead staging).
// EPI==1 epilogue: fp32 out[token][1024] (+bias), direct stores.
template<int EPI>
__global__ __launch_bounds__(256) void gemm128(
    const bf16* __restrict__ A,
    const bf16* __restrict__ Bw,
    const float* __restrict__ bias,
    float* __restrict__ outF,
    bf16* __restrict__ qb, bf16* __restrict__ kf, bf16* __restrict__ vf,
    int K)
{
    __shared__ __align__(16) char gsm[EPI == 0 ? 36864 : 32768];
    bf16* ct = (bf16*)gsm;                 // [128][144] padded C-tile (EPI==0)
    const int tid  = threadIdx.x;
    const int lane = tid & 63, w = tid >> 6;
    const int g = lane >> 4, lr = lane & 15;
    const int wr = w >> 1, wc = w & 1;
    int mt, nt;
    {
        int bid = blockIdx.x;
        int xcd = bid & 7, i = bid >> 3;
        if (EPI == 0) {                    // i in [0,96): 12 m-slices x 24 n
            mt = xcd * 4 + i / 24;
            nt = i % 24;
        } else {                           // i in [0,32): m-tiles 32 total
            mt = xcd * 4 + i / 8;          // 4 m-tiles per xcd... (32 m-tiles)
            nt = i % 8;
        }
    }
    // EPI==1: M=4096 -> 32 m-tiles; xcd*4 + i/8 covers 0..31 since i<32.
    const int mbase = mt * 128, nbase = nt * 128;

    f32x4 acc[4][4] = {};

    auto stg = [&](int buf, int it) {
        const bf16* Ag = A  + (size_t)mbase * K + it * 32;
        const bf16* Bg = Bw + (size_t)nbase * K + it * 32;
        bf16* as = (bf16*)(gsm + buf * 16384);
        bf16* bs = (bf16*)(gsm + buf * 16384 + 8192);
        int c0 = tid, c1 = 256 + tid;
        gload_lds16(Ag + (size_t)(c0 >> 2) * K + (c0 & 3) * 8, as + c0 * 8);
        gload_lds16(Bg + (size_t)(c0 >> 2) * K + (c0 & 3) * 8, bs + c0 * 8);
        gload_lds16(Ag + (size_t)(c1 >> 2) * K + (c1 & 3) * 8, as + c1 * 8);
        gload_lds16(Bg + (size_t)(c1 >> 2) * K + (c1 & 3) * 8, bs + c1 * 8);
    };

    const int nIt = K >> 5;
    stg(0, 0);
    __syncthreads();                       // publish K-step 0

    #pragma unroll 2
    for (int it = 0; it < nIt; ++it) {
        const int cur = it & 1;
        if (it + 1 < nIt) stg(cur ^ 1, it + 1);   // prefetch overlaps compute

        const bf16* as = (const bf16*)(gsm + cur * 16384);
        const bf16* bs = as + 4096;
        bf16x8 af[4], bfr[4];
        #pragma unroll
        for (int mi = 0; mi < 4; ++mi)
            af[mi] = *(const bf16x8*)(as + (wr * 64 + mi * 16 + lr) * 32 + g * 8);
        #pragma unroll
        for (int ni = 0; ni < 4; ++ni)
            bfr[ni] = *(const bf16x8*)(bs + (wc * 64 + ni * 16 + lr) * 32 + g * 8);
        #pragma unroll
        for (int mi = 0; mi < 4; ++mi)
            #pragma unroll
            for (int ni = 0; ni < 4; ++ni)
                acc[mi][ni] = __builtin_amdgcn_mfma_f32_16x16x32_bf16(
                    af[mi], bfr[ni], acc[mi][ni], 0, 0, 0);

        __syncthreads();   // vmcnt(0): stg(it+1) done; barrier: buf[cur] reusable
    }

    if (EPI == 1) {
        #pragma unroll
        for (int ni = 0; ni < 4; ++ni) {
            int e = nbase + wc * 64 + ni * 16 + lr;
            float bv = bias[e];
            #pragma unroll
            for (int mi = 0; mi < 4; ++mi) {
                #pragma unroll
                for (int r = 0; r < 4; ++r) {
                    int token = mbase + wr * 64 + mi * 16 + g * 4 + r;
                    outF[(size_t)token * 1024 + e] = acc[mi][ni][r] + bv;
                }
            }
        }
    } else {
        const int sec = nbase >> 10;                 // 0=Q 1=K 2=V (tile never straddles)
        #pragma unroll
        for (int ni = 0; ni < 4; ++ni) {
            int ec = wc * 64 + ni * 16 + lr;
            float bv = bias[nbase + ec];
            #pragma unroll
            for (int mi = 0; mi < 4; ++mi) {
                #pragma unroll
                for (int r = 0; r < 4; ++r) {
                    int tl = wr * 64 + mi * 16 + g * 4 + r;
                    float v = acc[mi][ni][r] + bv;
                    if (sec == 0) v *= QSCALE;
                    int row = (sec == 2) ? ec : tl;
                    int col = (sec == 2) ? tl : ec;
                    ct[row * 144 + col] = (bf16)v;
                }
            }
        }
        __syncthreads();
        const int b  = mbase >> 11;
        const int h0 = (nbase & 1023) >> 6;
        const int mb = mbase & 2047;
        #pragma unroll
        for (int si = 0; si < 8; ++si) {
            int c   = si * 256 + tid;
            int hh  = c >> 10;
            int w10 = c & 1023;
            int bh  = b * 16 + h0 + hh;
            int lrow, lcol;
            size_t gaddr;
            bf16* dst;
            if (sec == 0) {
                int nl = w10 >> 3, d0 = (w10 & 7) * 8;
                lrow = nl; lcol = hh * 64 + d0;
                gaddr = ((size_t)bh * 2048 + mb + nl) * 64 + d0;
                dst = qb;
            } else if (sec == 1) {
                int o = w10 * 8;
                int frag = o >> 9, l = (o >> 3) & 63;
                int nl = (frag >> 2) * 32 + (l & 31);
                int d0 = (frag & 3) * 16 + (l >> 5) * 8;
                lrow = nl; lcol = hh * 64 + d0;
                gaddr = ((size_t)(bh * 64 + (mb >> 5))) * 2048 + o;
                dst = kf;
            } else {
                int o = w10 * 8;
                int n6 = o >> 12, r2 = o & 4095;
                int d5 = r2 >> 11, r3 = r2 & 2047;
                int nc = r3 >> 9,  l  = (r3 >> 3) & 63;
                int d  = d5 * 32 + (l & 31);
                int n0 = n6 * 64 + nc * 16 + (l >> 5) * 8;
                lrow = hh * 64 + d; lcol = n0;
                gaddr = ((size_t)(bh * 32 + (mb >> 6))) * 4096 + o;
                dst = vf;
            }
            *(bf16x8*)(dst + gaddr) = *(const bf16x8*)(&ct[lrow * 144 + lcol]);
        }
    }
}

// ---------------- flash attention: 8 waves, KV-split, 64 q-rows per wave ----
// R18 body -- UNTOUCHED (closed at 43 us).
__global__ __launch_bounds__(512, 2) void attn32(
    const bf16* __restrict__ Q,    // [BH][N][64]
    const bf16* __restrict__ Kf,   // frag-major, 4096 elems per 64-kv chunk
    const bf16* __restrict__ Vf,   // frag-major, 4096 elems per 64-kv chunk
    bf16* __restrict__ Ao,         // [B*N][1024]
    int Nseq)
{
    __shared__ __align__(16) char smem[65536];
    bf16*  KsB = (bf16*)smem;              // [half][buf][4096]
    bf16*  VsB = (bf16*)(smem + 32768);    // [half][buf][4096]
    float* xch = (float*)smem;             // overlay: [4][64][36] partials
    bf16*  otp = (bf16*)(smem + 36864);    // overlay: [4][32][66] out transpose

    const int tid  = threadIdx.x;
    const int lane = tid & 63;
    const int u    = tid >> 6;             // wave 0..7
    const int half = u >> 2, qw = u & 3;
    const int hi = lane >> 5, ql = lane & 31;
    const int bid = blockIdx.x;            // 256 blocks
    const int xcd = bid & 7, ii = bid >> 3;
    const int bh = xcd * 4 + (ii >> 3), qc = ii & 7;
    const int h = bh & 15, b = bh >> 4;
    const int q0 = qc * 256 + qw * 64;

    const bf16* Qh  = Q  + (size_t)bh * Nseq * 64;
    const bf16* Kfh = Kf + (size_t)bh * Nseq * 64;
    const bf16* Vfh = Vf + (size_t)bh * Nseq * 64;

    bf16x8 qfA[4], qfB[4];
    #pragma unroll
    for (int c = 0; c < 4; ++c) {
        qfA[c] = *(const bf16x8*)(Qh + (size_t)(q0 + ql) * 64 + c * 16 + hi * 8);
        qfB[c] = *(const bf16x8*)(Qh + (size_t)(q0 + 32 + ql) * 64 + c * 16 + hi * 8);
    }

    bf16x8 vones;
    #pragma unroll
    for (int i = 0; i < 8; ++i) vones[i] = (bf16)1.0f;

    f32x16 o0A = {}, o1A = {}, laA = {};
    f32x16 o0B = {}, o1B = {}, laB = {};

    const int nch = (Nseq >> 6) >> 1;      // chunks per half (16, even)
    const int hk  = half * nch;

    auto stage = [&](int buf, int t) {
        const bf16* Kc = Kfh + (size_t)(hk + t) * 4096;
        const bf16* Vc = Vfh + (size_t)(hk + t) * 4096;
        bf16* kd = KsB + (half * 2 + buf) * 4096;
        bf16* vd = VsB + (half * 2 + buf) * 4096;
        int ht = tid & 255;
        gload_lds16(Kc + ht * 8,        kd + ht * 8);
        gload_lds16(Kc + 2048 + ht * 8, kd + 2048 + ht * 8);
        gload_lds16(Vc + ht * 8,        vd + ht * 8);
        gload_lds16(Vc + 2048 + ht * 8, vd + 2048 + ht * 8);
    };

    stage(0, 0);
    __syncthreads();                       // publish chunk 0 (vmcnt(0) + barrier)

    #pragma unroll 2
    for (int t = 0; t < nch; ++t) {
        const int cur = t & 1;
        if (t + 1 < nch) stage(cur ^ 1, t + 1);   // prefetch overlaps compute

        const bf16* kl = KsB + (half * 2 + cur) * 4096;
        const bf16* vl = VsB + (half * 2 + cur) * 4096;
        bf16x8 kin[8], vfr[8];
        #pragma unroll
        for (int i = 0; i < 8; ++i)
            kin[i] = *(const bf16x8*)(kl + i * 512 + lane * 8);
        #pragma unroll
        for (int i = 0; i < 8; ++i)
            vfr[i] = *(const bf16x8*)(vl + i * 512 + lane * 8);

        // ---- tile A ----
        {
            f32x16 s0 = {}, s1 = {};
            #pragma unroll
            for (int c = 0; c < 4; ++c) {
                s0 = __builtin_amdgcn_mfma_f32_32x32x16_bf16(kin[c],     qfA[c], s0, 0, 0, 0);
                s1 = __builtin_amdgcn_mfma_f32_32x32x16_bf16(kin[4 + c], qfA[c], s1, 0, 0, 0);
            }
            float p0[16], p1[16];
            #pragma unroll
            for (int r = 0; r < 16; ++r) { p0[r] = __builtin_amdgcn_exp2f(s0[r]); }
            #pragma unroll
            for (int r = 0; r < 16; ++r) { p1[r] = __builtin_amdgcn_exp2f(s1[r]); }
            bf16x8 pfr[4];
            #pragma unroll
            for (int f = 0; f < 4; ++f) {
                const float* pp = (f < 2) ? p0 : p1;
                const int base = (f & 1) * 8;
                union { uint32_t u[4]; bf16x8 v; } pw;
                #pragma unroll
                for (int wd = 0; wd < 2; ++wd) {
                    uint32_t X = pkbf(pp[base + 2*wd], pp[base + 2*wd + 1]);
                    uint32_t Y = pkbf(pp[base + 4 + 2*wd], pp[base + 4 + 2*wd + 1]);
                    auto rr = __builtin_amdgcn_permlane32_swap((int)X, (int)Y, false, false);
                    pw.u[wd]     = (uint32_t)rr[0];
                    pw.u[2 + wd] = (uint32_t)rr[1];
                }
                pfr[f] = pw.v;
            }
            #pragma unroll
            for (int f = 0; f < 4; ++f) {
                o0A = __builtin_amdgcn_mfma_f32_32x32x16_bf16(vfr[f],     pfr[f], o0A, 0, 0, 0);
                o1A = __builtin_amdgcn_mfma_f32_32x32x16_bf16(vfr[4 + f], pfr[f], o1A, 0, 0, 0);
                laA = __builtin_amdgcn_mfma_f32_32x32x16_bf16(vones,      pfr[f], laA, 0, 0, 0);
            }
        }
        // ---- tile B ----
        {
            f32x16 s0 = {}, s1 = {};
            #pragma unroll
            for (int c = 0; c < 4; ++c) {
                s0 = __builtin_amdgcn_mfma_f32_32x32x16_bf16(kin[c],     qfB[c], s0, 0, 0, 0);
                s1 = __builtin_amdgcn_mfma_f32_32x32x16_bf16(kin[4 + c], qfB[c], s1, 0, 0, 0);
            }
            float p0[16], p1[16];
            #pragma unroll
            for (int r = 0; r < 16; ++r) { p0[r] = __builtin_amdgcn_exp2f(s0[r]); }
            #pragma unroll
            for (int r = 0; r < 16; ++r) { p1[r] = __builtin_amdgcn_exp2f(s1[r]); }
            bf16x8 pfr[4];
            #pragma unroll
            for (int f = 0; f < 4; ++f) {
                const float* pp = (f < 2) ? p0 : p1;
                const int base = (f & 1) * 8;
                union { uint32_t u[4]; bf16x8 v; } pw;
                #pragma unroll
                for (int wd = 0; wd < 2; ++wd) {
                    uint32_t X = pkbf(pp[base + 2*wd], pp[base + 2*wd + 1]);
                    uint32_t Y = pkbf(pp[base + 4 + 2*wd], pp[base + 4 + 2*wd + 1]);
                    auto rr = __builtin_amdgcn_permlane32_swap((int)X, (int)Y, false, false);
                    pw.u[wd]     = (uint32_t)rr[0];
                    pw.u[2 + wd] = (uint32_t)rr[1];
                }
                pfr[f] = pw.v;
            }
            #pragma unroll
            for (int f = 0; f < 4; ++f) {
                o0B = __builtin_amdgcn_mfma_f32_32x32x16_bf16(vfr[f],     pfr[f], o0B, 0, 0, 0);
                o1B = __builtin_amdgcn_mfma_f32_32x32x16_bf16(vfr[4 + f], pfr[f], o1B, 0, 0, 0);
                laB = __builtin_amdgcn_mfma_f32_32x32x16_bf16(vones,      pfr[f], laB, 0, 0, 0);
            }
        }

        __syncthreads();   // vmcnt(0): stage(t+1) done; barrier: buf[cur] reusable
    }

    // ---- epilogue: two passes (tile A then B) through the same xch overlay ----
    auto finish = [&](const f32x16& po0, const f32x16& po1, const f32x16& pla, int qp) {
        float lsum = pla[0];               // ones-MFMA: denominator for q=ql
        __syncthreads();                   // staging dead / prior pass consumed
        if (half == 1) {
            float* xp = xch + ((size_t)(qw * 64 + lane)) * 36;
            *(f32x16*)(xp)      = po0;
            *(f32x16*)(xp + 16) = po1;
            xp[32] = lsum;
        }
        __syncthreads();
        if (half == 0) {
            const float* xp = xch + ((size_t)(qw * 64 + lane)) * 36;
            f32x16 oa = *(const f32x16*)(xp);
            f32x16 ob = *(const f32x16*)(xp + 16);
            f32x16 m0 = po0 + oa;
            f32x16 m1 = po1 + ob;
            float ls = lsum + xp[32];
            float linv = __builtin_amdgcn_rcpf(ls);
            #pragma unroll
            for (int qd = 0; qd < 4; ++qd) {
                int dbase = 8 * qd + 4 * hi;
                bf16* orow = otp + (qw * 32 + ql) * 66;
                *(uint32_t*)(orow + dbase)          = pkbf(m0[4*qd] * linv,   m0[4*qd+1] * linv);
                *(uint32_t*)(orow + dbase + 2)      = pkbf(m0[4*qd+2] * linv, m0[4*qd+3] * linv);
                *(uint32_t*)(orow + 32 + dbase)     = pkbf(m1[4*qd] * linv,   m1[4*qd+1] * linv);
                *(uint32_t*)(orow + 32 + dbase + 2) = pkbf(m1[4*qd+2] * linv, m1[4*qd+3] * linv);
            }
            __asm__ volatile("s_waitcnt lgkmcnt(0)" ::: "memory");
            const int t = lane >> 1, e = lane & 1;
            uint32_t rw[16];
            #pragma unroll
            for (int j = 0; j < 16; ++j)
                rw[j] = *(const uint32_t*)(otp + (qw * 32 + t) * 66 + e * 32 + 2 * j);
            size_t gbase = (size_t)(b * Nseq + q0 + qp + t) * 1024 + h * 64 + e * 32;
            #pragma unroll
            for (int v = 0; v < 4; ++v) {
                u32x4 sv = { rw[4*v], rw[4*v+1], rw[4*v+2], rw[4*v+3] };
                *(u32x4*)(Ao + gbase + v * 8) = sv;
            }
        }
    };
    finish(o0A, o1A, laA, 0);
    finish(o0B, o1B, laB, 32);
}

extern "C" void kernel_launch(void* const* d_in, const int* in_sizes, int n_in,
                              void* d_out, int out_size, void* d_ws, size_t ws_size,
                              hipStream_t stream) {
    const float* x      = (const float*)d_in[0];
    const float* qkv_w  = (const float*)d_in[1];
    const float* qkv_b  = (const float*)d_in[2];
    const float* proj_w = (const float*)d_in[3];
    const float* proj_b = (const float*)d_in[4];
    float* out = (float*)d_out;

    char* ws = (char*)d_ws;
    bf16* xb    = (bf16*)(ws);                       // 8 MB  [4096][1024]
    bf16* wqkv  = (bf16*)(ws + ((size_t)8  << 20));  // 6 MB  [3072][1024]
    bf16* wproj = (bf16*)(ws + ((size_t)14 << 20));  // 2 MB  [1024][1024]
    bf16* qb    = (bf16*)(ws + ((size_t)16 << 20));  // 8 MB  [32][2048][64]
    bf16* kf    = (bf16*)(ws + ((size_t)24 << 20));  // 8 MB  fragment-major K
    bf16* vf    = (bf16*)(ws + ((size_t)32 << 20));  // 8 MB  fragment-major V
    bf16* att   = (bf16*)(ws);                       // 8 MB  [4096][1024] (over xb)

    cast_all<<<dim3(2048), dim3(256), 0, stream>>>(x, qkv_w, proj_w, xb, wqkv, wproj);

    gemm128<0><<<dim3(768), dim3(256), 0, stream>>>(
        xb, wqkv, qkv_b, (float*)nullptr, qb, kf, vf, 1024);

    attn32<<<dim3(256), dim3(512), 0, stream>>>(qb, kf, vf, att, 2048);

    gemm128<1><<<dim3(256), dim3(256), 0, stream>>>(
        att, wproj, proj_b, out, (bf16*)nullptr, (bf16*)nullptr, (bf16*)nullptr, 1024);
}